// Round 8
// baseline (409.364 us; speedup 1.0000x reference)
//
#include <hip/hip_runtime.h>
#include <math.h>

typedef __attribute__((ext_vector_type(8))) short short8;
typedef __attribute__((ext_vector_type(4))) float f32x4;

#define NFEAT 512
#define HID_ALL 512
#define NCLASS 500
#define ALPHA 0.2f
#define BM 128
#define BN 128

__device__ __forceinline__ ushort f32_to_bf16(float f) {
    union { float f; unsigned u; } v; v.f = f;
    unsigned u = v.u;
    unsigned r = (u + 0x7FFFu + ((u >> 16) & 1u)) >> 16;
    return (ushort)r;
}
__device__ __forceinline__ void unpack8(uint4 u, float* f) {
    f[0] = __uint_as_float(u.x << 16);
    f[1] = __uint_as_float(u.x & 0xFFFF0000u);
    f[2] = __uint_as_float(u.y << 16);
    f[3] = __uint_as_float(u.y & 0xFFFF0000u);
    f[4] = __uint_as_float(u.z << 16);
    f[5] = __uint_as_float(u.z & 0xFFFF0000u);
    f[6] = __uint_as_float(u.w << 16);
    f[7] = __uint_as_float(u.w & 0xFFFF0000u);
}
__device__ __forceinline__ float att_w(float lg) {
    return __expf(lg > 0.f ? -lg : -ALPHA * lg);
}
__device__ __forceinline__ void gload16(const void* g, void* l) {
    __builtin_amdgcn_global_load_lds(
        (const __attribute__((address_space(1))) unsigned int*)g,
        (__attribute__((address_space(3))) unsigned int*)l,
        16, 0, 0);
}

// fused prep: build both weight transposes + zero CSR counters
__global__ void prep_kernel(const float* __restrict__ W, ushort* __restrict__ W1T,
                            const float* __restrict__ oW, ushort* __restrict__ W2T,
                            int* __restrict__ cnt, int* __restrict__ cur, int N) {
    int idx = blockIdx.x * blockDim.x + threadIdx.x;
    if (idx < 512 * 512) {
        int c = idx >> 9, f = idx & 511;
        int head = c >> 6, k = c & 63;
        W1T[idx] = f32_to_bf16(W[(head << 15) + (f << 6) + k]);
        float v = (c < NCLASS) ? oW[f * NCLASS + c] : 0.f;
        W2T[idx] = f32_to_bf16(v);
    }
    if (idx < N) { cnt[idx] = 0; cur[idx] = 0; }
}

__global__ void cast_feat_kernel(const float* __restrict__ in, ushort* __restrict__ out, int n4) {
    int stride = gridDim.x * blockDim.x;
    for (int i = blockIdx.x * blockDim.x + threadIdx.x; i < n4; i += stride) {
        float4 v = reinterpret_cast<const float4*>(in)[i];
        ushort4 o;
        o.x = f32_to_bf16(v.x); o.y = f32_to_bf16(v.y);
        o.z = f32_to_bf16(v.z); o.w = f32_to_bf16(v.w);
        reinterpret_cast<ushort4*>(out)[i] = o;
    }
}

__global__ void edge_count_kernel(const int* __restrict__ src, int* __restrict__ cnt, int E) {
    int e = blockIdx.x * blockDim.x + threadIdx.x;
    if (e < E) atomicAdd(&cnt[src[e]], 1);
}

__global__ __launch_bounds__(1024) void scan_kernel(const int* __restrict__ cnt,
                                                    int* __restrict__ rowptr, int n) {
    __shared__ int part[1024];
    int t = threadIdx.x;
    int chunk = (n + 1023) >> 10;
    int beg = t * chunk;
    int end = beg + chunk; if (end > n) end = n;
    int s = 0;
    for (int i = beg; i < end; i++) s += cnt[i];
    part[t] = s;
    __syncthreads();
    for (int off = 1; off < 1024; off <<= 1) {
        int v = part[t];
        int add = (t >= off) ? part[t - off] : 0;
        __syncthreads();
        part[t] = v + add;
        __syncthreads();
    }
    int base = (t > 0) ? part[t - 1] : 0;
    for (int i = beg; i < end; i++) { rowptr[i] = base; base += cnt[i]; }
    if (t == 1023) rowptr[n] = part[1023];
}

__global__ void scatter_kernel(const int* __restrict__ src, const int* __restrict__ dst,
                               const int* __restrict__ rowptr, int* __restrict__ cur,
                               int* __restrict__ colidx, int E) {
    int e = blockIdx.x * blockDim.x + threadIdx.x;
    if (e >= E) return;
    int s = src[e];
    int p = rowptr[s] + atomicAdd(&cur[s], 1);
    colidx[p] = dst[e];
}

// C[M,512] = A[M,512] @ B[512,512], B given as Bt[col][k]. bf16 MFMA, f32 accum.
// m97-style: global_load_lds width=16 into linear LDS [128][32].
__global__ __launch_bounds__(256) void gemm_bf16_kernel(const ushort* __restrict__ A,
                                                        const ushort* __restrict__ Bt,
                                                        ushort* __restrict__ C, int M) {
    __shared__ ushort As[BM * 32];
    __shared__ ushort Bs[BN * 32];
    int m0 = blockIdx.x * BM;
    int n0 = blockIdx.y * BN;
    int t = threadIdx.x;
    int lane = t & 63, wid = t >> 6;
    int wr = wid >> 1, wc = wid & 1;
    int srow = lane >> 2;
    int skc = (lane & 3) << 3;
    f32x4 acc[4][4] = {};
    for (int k0 = 0; k0 < 512; k0 += 32) {
        __syncthreads();
#pragma unroll
        for (int j = 0; j < 2; j++) {
            int rb = j * 64 + wid * 16;
            int rowA = m0 + rb + srow; if (rowA >= M) rowA = M - 1;
            gload16(&A[(size_t)rowA * 512 + k0 + skc], &As[rb * 32]);
            int rowB = n0 + rb + srow;
            gload16(&Bt[(size_t)rowB * 512 + k0 + skc], &Bs[rb * 32]);
        }
        __syncthreads();
        int ko = (lane >> 4) << 3;
        int r15 = lane & 15;
        short8 af[4], bfr[4];
#pragma unroll
        for (int mi = 0; mi < 4; mi++)
            af[mi] = *reinterpret_cast<const short8*>(&As[((wr << 6) + mi * 16 + r15) * 32 + ko]);
#pragma unroll
        for (int ni = 0; ni < 4; ni++)
            bfr[ni] = *reinterpret_cast<const short8*>(&Bs[((wc << 6) + ni * 16 + r15) * 32 + ko]);
#pragma unroll
        for (int mi = 0; mi < 4; mi++)
#pragma unroll
            for (int ni = 0; ni < 4; ni++)
                acc[mi][ni] = __builtin_amdgcn_mfma_f32_16x16x32_bf16(af[mi], bfr[ni], acc[mi][ni], 0, 0, 0);
    }
    int fr = (lane >> 4) << 2;
    int col = lane & 15;
#pragma unroll
    for (int mi = 0; mi < 4; mi++)
#pragma unroll
        for (int ni = 0; ni < 4; ni++)
#pragma unroll
            for (int r = 0; r < 4; r++) {
                int grow = m0 + (wr << 6) + mi * 16 + fr + r;
                if (grow < M) {
                    int gcol = n0 + (wc << 6) + ni * 16 + col;
                    C[(size_t)grow * 512 + gcol] = f32_to_bf16(acc[mi][ni][r]);
                }
            }
}

// s1[n,h] = sum_k h1[n, h*64+k]*a[h,k];  d1 with a[h,64+k].  1 wave per node.
__global__ __launch_bounds__(256) void scores1_kernel(const ushort* __restrict__ h1,
                                                      const float* __restrict__ a,
                                                      float* __restrict__ s1, float* __restrict__ d1,
                                                      int N) {
    int lane = threadIdx.x & 63;
    int n = (blockIdx.x << 2) + (threadIdx.x >> 6);
    if (n >= N) return;
    int h = lane >> 3, j = lane & 7;
    uint4 u = *reinterpret_cast<const uint4*>(&h1[(size_t)n * 512 + lane * 8]);
    float f[8]; unpack8(u, f);
    const float* ah = a + (h << 7) + (j << 3);
    float ss = 0.f, dd = 0.f;
#pragma unroll
    for (int q = 0; q < 8; q++) { ss += f[q] * ah[q]; dd += f[q] * ah[64 + q]; }
#pragma unroll
    for (int off = 1; off < 8; off <<= 1) {
        ss += __shfl_xor(ss, off);
        dd += __shfl_xor(dd, off);
    }
    if (j == 0) { s1[(n << 3) + h] = ss; d1[(n << 3) + h] = dd; }
}

// layer-1 aggregation over node range [nb, ne), edge loop unrolled x4.
__global__ __launch_bounds__(256) void agg1_kernel(const ushort* __restrict__ h1,
                                                   const float* __restrict__ s1,
                                                   const float* __restrict__ d1,
                                                   const int* __restrict__ rowptr,
                                                   const int* __restrict__ colidx,
                                                   ushort* __restrict__ x, int nb, int ne) {
    int lane = threadIdx.x & 63;
    int n = nb + (blockIdx.x << 2) + (threadIdx.x >> 6);
    if (n >= ne) return;
    int h = lane >> 3;
    float sn = s1[(n << 3) + h];
    float acc[8] = {0.f, 0.f, 0.f, 0.f, 0.f, 0.f, 0.f, 0.f};
    float rsum = 0.f;
    int beg = rowptr[n], end = rowptr[n + 1];
    int i = beg;
    for (; i + 4 <= end; i += 4) {
        int dv0 = colidx[i], dv1 = colidx[i + 1], dv2 = colidx[i + 2], dv3 = colidx[i + 3];
        float g0 = d1[(dv0 << 3) + h];
        float g1 = d1[(dv1 << 3) + h];
        float g2 = d1[(dv2 << 3) + h];
        float g3 = d1[(dv3 << 3) + h];
        uint4 u0 = *reinterpret_cast<const uint4*>(&h1[(size_t)dv0 * 512 + lane * 8]);
        uint4 u1 = *reinterpret_cast<const uint4*>(&h1[(size_t)dv1 * 512 + lane * 8]);
        uint4 u2 = *reinterpret_cast<const uint4*>(&h1[(size_t)dv2 * 512 + lane * 8]);
        uint4 u3 = *reinterpret_cast<const uint4*>(&h1[(size_t)dv3 * 512 + lane * 8]);
        float w0 = att_w(sn + g0), w1 = att_w(sn + g1), w2 = att_w(sn + g2), w3 = att_w(sn + g3);
        rsum += (w0 + w1) + (w2 + w3);
        float f[8];
        unpack8(u0, f);
#pragma unroll
        for (int q = 0; q < 8; q++) acc[q] += w0 * f[q];
        unpack8(u1, f);
#pragma unroll
        for (int q = 0; q < 8; q++) acc[q] += w1 * f[q];
        unpack8(u2, f);
#pragma unroll
        for (int q = 0; q < 8; q++) acc[q] += w2 * f[q];
        unpack8(u3, f);
#pragma unroll
        for (int q = 0; q < 8; q++) acc[q] += w3 * f[q];
    }
    for (; i < end; i++) {
        int dv = colidx[i];
        float w = att_w(sn + d1[(dv << 3) + h]);
        rsum += w;
        uint4 u = *reinterpret_cast<const uint4*>(&h1[(size_t)dv * 512 + lane * 8]);
        float f[8]; unpack8(u, f);
#pragma unroll
        for (int q = 0; q < 8; q++) acc[q] += w * f[q];
    }
    float inv = 1.f / rsum;
    uint ov[4];
#pragma unroll
    for (int p = 0; p < 4; p++) {
        float v0 = acc[2 * p] * inv;     v0 = v0 > 0.f ? v0 : __expf(v0) - 1.f;
        float v1 = acc[2 * p + 1] * inv; v1 = v1 > 0.f ? v1 : __expf(v1) - 1.f;
        ov[p] = (uint)f32_to_bf16(v0) | ((uint)f32_to_bf16(v1) << 16);
    }
    uint4 o; o.x = ov[0]; o.y = ov[1]; o.z = ov[2]; o.w = ov[3];
    *reinterpret_cast<uint4*>(&x[(size_t)n * 512 + lane * 8]) = o;
}

// s2[n] = sum_c h2[n,c]*out_a[c];  d2 with out_a[500+c].  1 wave per node.
__global__ __launch_bounds__(256) void scores2_kernel(const ushort* __restrict__ h2,
                                                      const float* __restrict__ oa,
                                                      float* __restrict__ s2, float* __restrict__ d2,
                                                      int N) {
    int lane = threadIdx.x & 63;
    int n = (blockIdx.x << 2) + (threadIdx.x >> 6);
    if (n >= N) return;
    int c0 = lane * 8;
    uint4 u = *reinterpret_cast<const uint4*>(&h2[(size_t)n * 512 + c0]);
    float f[8]; unpack8(u, f);
    float ss = 0.f, dd = 0.f;
#pragma unroll
    for (int q = 0; q < 8; q++) {
        int c = c0 + q;
        if (c < NCLASS) { ss += f[q] * oa[c]; dd += f[q] * oa[NCLASS + c]; }
    }
#pragma unroll
    for (int off = 1; off < 64; off <<= 1) {
        ss += __shfl_xor(ss, off);
        dd += __shfl_xor(dd, off);
    }
    if (lane == 0) { s2[n] = ss; d2[n] = dd; }
}

// layer-2 aggregation + final elu over node range [nb, ne), edge loop unrolled x4.
__global__ __launch_bounds__(256) void agg2_kernel(const ushort* __restrict__ h2,
                                                   const float* __restrict__ s2,
                                                   const float* __restrict__ d2,
                                                   const int* __restrict__ rowptr,
                                                   const int* __restrict__ colidx,
                                                   float* __restrict__ out, int nb, int ne) {
    int lane = threadIdx.x & 63;
    int n = nb + (blockIdx.x << 2) + (threadIdx.x >> 6);
    if (n >= ne) return;
    int c0 = lane * 8;
    float sn = s2[n];
    float acc[8] = {0.f, 0.f, 0.f, 0.f, 0.f, 0.f, 0.f, 0.f};
    float rsum = 0.f;
    int beg = rowptr[n], end = rowptr[n + 1];
    int i = beg;
    for (; i + 4 <= end; i += 4) {
        int dv0 = colidx[i], dv1 = colidx[i + 1], dv2 = colidx[i + 2], dv3 = colidx[i + 3];
        float g0 = d2[dv0], g1 = d2[dv1], g2 = d2[dv2], g3 = d2[dv3];
        uint4 u0 = *reinterpret_cast<const uint4*>(&h2[(size_t)dv0 * 512 + c0]);
        uint4 u1 = *reinterpret_cast<const uint4*>(&h2[(size_t)dv1 * 512 + c0]);
        uint4 u2 = *reinterpret_cast<const uint4*>(&h2[(size_t)dv2 * 512 + c0]);
        uint4 u3 = *reinterpret_cast<const uint4*>(&h2[(size_t)dv3 * 512 + c0]);
        float w0 = att_w(sn + g0), w1 = att_w(sn + g1), w2 = att_w(sn + g2), w3 = att_w(sn + g3);
        rsum += (w0 + w1) + (w2 + w3);
        float f[8];
        unpack8(u0, f);
#pragma unroll
        for (int q = 0; q < 8; q++) acc[q] += w0 * f[q];
        unpack8(u1, f);
#pragma unroll
        for (int q = 0; q < 8; q++) acc[q] += w1 * f[q];
        unpack8(u2, f);
#pragma unroll
        for (int q = 0; q < 8; q++) acc[q] += w2 * f[q];
        unpack8(u3, f);
#pragma unroll
        for (int q = 0; q < 8; q++) acc[q] += w3 * f[q];
    }
    for (; i < end; i++) {
        int dv = colidx[i];
        float w = att_w(sn + d2[dv]);
        rsum += w;
        uint4 u = *reinterpret_cast<const uint4*>(&h2[(size_t)dv * 512 + c0]);
        float f[8]; unpack8(u, f);
#pragma unroll
        for (int q = 0; q < 8; q++) acc[q] += w * f[q];
    }
    float inv = 1.f / rsum;
#pragma unroll
    for (int q = 0; q < 8; q++) {
        int c = c0 + q;
        if (c < NCLASS) {
            float v = acc[q] * inv;
            v = v > 0.f ? v : __expf(v) - 1.f;
            out[(size_t)n * NCLASS + c] = v;
        }
    }
}

extern "C" void kernel_launch(void* const* d_in, const int* in_sizes, int n_in,
                              void* d_out, int out_size, void* d_ws, size_t ws_size,
                              hipStream_t stream) {
    const float* features = (const float*)d_in[0];
    const int* edge_index = (const int*)d_in[1];
    const float* W = (const float*)d_in[2];
    const float* a = (const float*)d_in[3];
    const float* out_W = (const float*)d_in[4];
    const float* out_a = (const float*)d_in[5];
    float* out = (float*)d_out;

    int N = in_sizes[0] / NFEAT;
    int E = in_sizes[1] / 2;
    const int* src = edge_index;
    const int* dst = edge_index + E;

    char* base = (char*)d_ws;
    size_t off = 0;
    auto alloc = [&](size_t bytes) -> char* {
        char* r = base + off;
        off += (bytes + 255) & ~(size_t)255;
        return r;
    };
    ushort* featb = (ushort*)alloc((size_t)N * 512 * 2);
    ushort* h1b   = (ushort*)alloc((size_t)N * 512 * 2);
    ushort* xb    = (ushort*)alloc((size_t)N * 512 * 2);
    ushort* h2b   = featb;  // features-bf16 dead after GEMM-1; alias to cut peak ws
    ushort* w1t   = (ushort*)alloc(512 * 512 * 2);
    ushort* w2t   = (ushort*)alloc(512 * 512 * 2);
    float* s1 = (float*)alloc((size_t)N * 8 * 4);
    float* d1 = (float*)alloc((size_t)N * 8 * 4);
    float* s2 = (float*)alloc((size_t)N * 4);
    float* d2 = (float*)alloc((size_t)N * 4);
    int* rowptr = (int*)alloc((size_t)(N + 1) * 4);
    int* colidx = (int*)alloc((size_t)E * 4);
    int* cnt = (int*)alloc((size_t)N * 4);
    int* cur = (int*)alloc((size_t)N * 4);
    if (off > ws_size) return;

    prep_kernel<<<1024, 256, 0, stream>>>(W, w1t, out_W, w2t, cnt, cur, N);
    cast_feat_kernel<<<2048, 256, 0, stream>>>(features, featb, N * 512 / 4);
    edge_count_kernel<<<(E + 255) / 256, 256, 0, stream>>>(src, cnt, E);
    scan_kernel<<<1, 1024, 0, stream>>>(cnt, rowptr, N);
    scatter_kernel<<<(E + 255) / 256, 256, 0, stream>>>(src, dst, rowptr, cur, colidx, E);

    int half = (N + 1) / 2;
    int g1 = (half + 3) / 4, g2 = (N - half + 3) / 4;
    dim3 gemm_grid((N + BM - 1) / BM, HID_ALL / BN);
    gemm_bf16_kernel<<<gemm_grid, 256, 0, stream>>>(featb, w1t, h1b, N);
    scores1_kernel<<<(N + 3) / 4, 256, 0, stream>>>(h1b, a, s1, d1, N);
    agg1_kernel<<<g1, 256, 0, stream>>>(h1b, s1, d1, rowptr, colidx, xb, 0, half);
    agg1_kernel<<<g2, 256, 0, stream>>>(h1b, s1, d1, rowptr, colidx, xb, half, N);
    gemm_bf16_kernel<<<gemm_grid, 256, 0, stream>>>(xb, w2t, h2b, N);
    scores2_kernel<<<(N + 3) / 4, 256, 0, stream>>>(h2b, out_a, s2, d2, N);
    agg2_kernel<<<g1, 256, 0, stream>>>(h2b, s2, d2, rowptr, colidx, out, 0, half);
    agg2_kernel<<<g2, 256, 0, stream>>>(h2b, s2, d2, rowptr, colidx, out, half, N);
}

// Round 9
// 382.093 us; speedup vs baseline: 1.0714x; 1.0714x over previous
//
#include <hip/hip_runtime.h>
#include <math.h>

typedef __attribute__((ext_vector_type(8))) short short8;
typedef __attribute__((ext_vector_type(4))) float f32x4;

#define NFEAT 512
#define HID_ALL 512
#define NCLASS 500
#define ALPHA 0.2f
#define BM 128
#define BN 128

__device__ __forceinline__ ushort f32_to_bf16(float f) {
    union { float f; unsigned u; } v; v.f = f;
    unsigned u = v.u;
    unsigned r = (u + 0x7FFFu + ((u >> 16) & 1u)) >> 16;
    return (ushort)r;
}
__device__ __forceinline__ void unpack8(uint4 u, float* f) {
    f[0] = __uint_as_float(u.x << 16);
    f[1] = __uint_as_float(u.x & 0xFFFF0000u);
    f[2] = __uint_as_float(u.y << 16);
    f[3] = __uint_as_float(u.y & 0xFFFF0000u);
    f[4] = __uint_as_float(u.z << 16);
    f[5] = __uint_as_float(u.z & 0xFFFF0000u);
    f[6] = __uint_as_float(u.w << 16);
    f[7] = __uint_as_float(u.w & 0xFFFF0000u);
}
__device__ __forceinline__ float att_w(float lg) {
    return __expf(lg > 0.f ? -lg : -ALPHA * lg);
}
__device__ __forceinline__ void gload16(const void* g, void* l) {
    __builtin_amdgcn_global_load_lds(
        (const __attribute__((address_space(1))) unsigned int*)g,
        (__attribute__((address_space(3))) unsigned int*)l,
        16, 0, 0);
}

// fused prep: weight transposes + padded out_a tables + zero CSR counters
__global__ void prep_kernel(const float* __restrict__ W, ushort* __restrict__ W1T,
                            const float* __restrict__ oW, ushort* __restrict__ W2T,
                            const float* __restrict__ oa, float* __restrict__ oas,
                            float* __restrict__ oad,
                            int* __restrict__ cnt, int* __restrict__ cur, int N) {
    int idx = blockIdx.x * blockDim.x + threadIdx.x;
    if (idx < 512 * 512) {
        int c = idx >> 9, f = idx & 511;
        int head = c >> 6, k = c & 63;
        W1T[idx] = f32_to_bf16(W[(head << 15) + (f << 6) + k]);
        float v = (c < NCLASS) ? oW[f * NCLASS + c] : 0.f;
        W2T[idx] = f32_to_bf16(v);
    }
    if (idx < 512) {
        oas[idx] = (idx < NCLASS) ? oa[idx] : 0.f;
        oad[idx] = (idx < NCLASS) ? oa[NCLASS + idx] : 0.f;
    }
    if (idx < N) { cnt[idx] = 0; cur[idx] = 0; }
}

__global__ void cast_feat_kernel(const float* __restrict__ in, ushort* __restrict__ out, int n4) {
    int stride = gridDim.x * blockDim.x;
    for (int i = blockIdx.x * blockDim.x + threadIdx.x; i < n4; i += stride) {
        float4 v = reinterpret_cast<const float4*>(in)[i];
        ushort4 o;
        o.x = f32_to_bf16(v.x); o.y = f32_to_bf16(v.y);
        o.z = f32_to_bf16(v.z); o.w = f32_to_bf16(v.w);
        reinterpret_cast<ushort4*>(out)[i] = o;
    }
}

__global__ void edge_count_kernel(const int* __restrict__ src, int* __restrict__ cnt, int E) {
    int e = blockIdx.x * blockDim.x + threadIdx.x;
    if (e < E) atomicAdd(&cnt[src[e]], 1);
}

__global__ __launch_bounds__(1024) void scan_kernel(const int* __restrict__ cnt,
                                                    int* __restrict__ rowptr, int n) {
    __shared__ int part[1024];
    int t = threadIdx.x;
    int chunk = (n + 1023) >> 10;
    int beg = t * chunk;
    int end = beg + chunk; if (end > n) end = n;
    int s = 0;
    for (int i = beg; i < end; i++) s += cnt[i];
    part[t] = s;
    __syncthreads();
    for (int off = 1; off < 1024; off <<= 1) {
        int v = part[t];
        int add = (t >= off) ? part[t - off] : 0;
        __syncthreads();
        part[t] = v + add;
        __syncthreads();
    }
    int base = (t > 0) ? part[t - 1] : 0;
    for (int i = beg; i < end; i++) { rowptr[i] = base; base += cnt[i]; }
    if (t == 1023) rowptr[n] = part[1023];
}

__global__ void scatter_kernel(const int* __restrict__ src, const int* __restrict__ dst,
                               const int* __restrict__ rowptr, int* __restrict__ cur,
                               int* __restrict__ colidx, int E) {
    int e = blockIdx.x * blockDim.x + threadIdx.x;
    if (e >= E) return;
    int s = src[e];
    int p = rowptr[s] + atomicAdd(&cur[s], 1);
    colidx[p] = dst[e];
}

// C[M,512] = A[M,512] @ B[512,512], B given as Bt[col][k]. bf16 MFMA, f32 accum.
__global__ __launch_bounds__(256) void gemm_bf16_kernel(const ushort* __restrict__ A,
                                                        const ushort* __restrict__ Bt,
                                                        ushort* __restrict__ C, int M) {
    __shared__ ushort As[BM * 32];
    __shared__ ushort Bs[BN * 32];
    int m0 = blockIdx.x * BM;
    int n0 = blockIdx.y * BN;
    int t = threadIdx.x;
    int lane = t & 63, wid = t >> 6;
    int wr = wid >> 1, wc = wid & 1;
    int srow = lane >> 2;
    int skc = (lane & 3) << 3;
    f32x4 acc[4][4] = {};
    for (int k0 = 0; k0 < 512; k0 += 32) {
        __syncthreads();
#pragma unroll
        for (int j = 0; j < 2; j++) {
            int rb = j * 64 + wid * 16;
            int rowA = m0 + rb + srow; if (rowA >= M) rowA = M - 1;
            gload16(&A[(size_t)rowA * 512 + k0 + skc], &As[rb * 32]);
            int rowB = n0 + rb + srow;
            gload16(&Bt[(size_t)rowB * 512 + k0 + skc], &Bs[rb * 32]);
        }
        __syncthreads();
        int ko = (lane >> 4) << 3;
        int r15 = lane & 15;
        short8 af[4], bfr[4];
#pragma unroll
        for (int mi = 0; mi < 4; mi++)
            af[mi] = *reinterpret_cast<const short8*>(&As[((wr << 6) + mi * 16 + r15) * 32 + ko]);
#pragma unroll
        for (int ni = 0; ni < 4; ni++)
            bfr[ni] = *reinterpret_cast<const short8*>(&Bs[((wc << 6) + ni * 16 + r15) * 32 + ko]);
#pragma unroll
        for (int mi = 0; mi < 4; mi++)
#pragma unroll
            for (int ni = 0; ni < 4; ni++)
                acc[mi][ni] = __builtin_amdgcn_mfma_f32_16x16x32_bf16(af[mi], bfr[ni], acc[mi][ni], 0, 0, 0);
    }
    int fr = (lane >> 4) << 2;
    int col = lane & 15;
#pragma unroll
    for (int mi = 0; mi < 4; mi++)
#pragma unroll
        for (int ni = 0; ni < 4; ni++)
#pragma unroll
            for (int r = 0; r < 4; r++) {
                int grow = m0 + (wr << 6) + mi * 16 + fr + r;
                if (grow < M) {
                    int gcol = n0 + (wc << 6) + ni * 16 + col;
                    C[(size_t)grow * 512 + gcol] = f32_to_bf16(acc[mi][ni][r]);
                }
            }
}

// lane-per-node scores, no cross-lane ops. s1[n,h] = h1[n, h*64:..] . a[h,:64], d1 likewise.
__global__ __launch_bounds__(256) void scores1_kernel(const ushort* __restrict__ h1,
                                                      const float* __restrict__ a,
                                                      float* __restrict__ s1, float* __restrict__ d1,
                                                      int N) {
    int n = blockIdx.x * blockDim.x + threadIdx.x;
    if (n >= N) return;
    const uint4* row = reinterpret_cast<const uint4*>(h1 + (size_t)n * 512);
    float ss[8], dd[8];
#pragma unroll
    for (int h = 0; h < 8; h++) {
        float as = 0.f, ad = 0.f;
#pragma unroll
        for (int ch = 0; ch < 8; ch++) {
            uint4 u = row[(h << 3) + ch];
            float f[8]; unpack8(u, f);
            const float* ah = a + (h << 7) + (ch << 3);
#pragma unroll
            for (int q = 0; q < 8; q++) { as += f[q] * ah[q]; ad += f[q] * ah[64 + q]; }
        }
        ss[h] = as; dd[h] = ad;
    }
    float4* s1v = reinterpret_cast<float4*>(s1 + ((size_t)n << 3));
    s1v[0] = make_float4(ss[0], ss[1], ss[2], ss[3]);
    s1v[1] = make_float4(ss[4], ss[5], ss[6], ss[7]);
    float4* d1v = reinterpret_cast<float4*>(d1 + ((size_t)n << 3));
    d1v[0] = make_float4(dd[0], dd[1], dd[2], dd[3]);
    d1v[1] = make_float4(dd[4], dd[5], dd[6], dd[7]);
}

// lane-per-node scores2: s2[n] = h2[n,:] . oas, d2[n] = h2[n,:] . oad (padded tables).
__global__ __launch_bounds__(256) void scores2_kernel(const ushort* __restrict__ h2,
                                                      const float* __restrict__ oas,
                                                      const float* __restrict__ oad,
                                                      float* __restrict__ s2, float* __restrict__ d2,
                                                      int N) {
    int n = blockIdx.x * blockDim.x + threadIdx.x;
    if (n >= N) return;
    const uint4* row = reinterpret_cast<const uint4*>(h2 + (size_t)n * 512);
    float ss = 0.f, dd = 0.f;
#pragma unroll
    for (int ch = 0; ch < 64; ch++) {
        uint4 u = row[ch];
        float f[8]; unpack8(u, f);
        const float* as = oas + (ch << 3);
        const float* ad = oad + (ch << 3);
#pragma unroll
        for (int q = 0; q < 8; q++) { ss += f[q] * as[q]; dd += f[q] * ad[q]; }
    }
    s2[n] = ss; d2[n] = dd;
}

// layer-1 aggregation over node range [nb, ne), edge loop unrolled x4.
__global__ __launch_bounds__(256) void agg1_kernel(const ushort* __restrict__ h1,
                                                   const float* __restrict__ s1,
                                                   const float* __restrict__ d1,
                                                   const int* __restrict__ rowptr,
                                                   const int* __restrict__ colidx,
                                                   ushort* __restrict__ x, int nb, int ne) {
    int lane = threadIdx.x & 63;
    int n = nb + (blockIdx.x << 2) + (threadIdx.x >> 6);
    if (n >= ne) return;
    int h = lane >> 3;
    float sn = s1[(n << 3) + h];
    float acc[8] = {0.f, 0.f, 0.f, 0.f, 0.f, 0.f, 0.f, 0.f};
    float rsum = 0.f;
    int beg = rowptr[n], end = rowptr[n + 1];
    int i = beg;
    for (; i + 4 <= end; i += 4) {
        int dv0 = colidx[i], dv1 = colidx[i + 1], dv2 = colidx[i + 2], dv3 = colidx[i + 3];
        float g0 = d1[(dv0 << 3) + h];
        float g1 = d1[(dv1 << 3) + h];
        float g2 = d1[(dv2 << 3) + h];
        float g3 = d1[(dv3 << 3) + h];
        uint4 u0 = *reinterpret_cast<const uint4*>(&h1[(size_t)dv0 * 512 + lane * 8]);
        uint4 u1 = *reinterpret_cast<const uint4*>(&h1[(size_t)dv1 * 512 + lane * 8]);
        uint4 u2 = *reinterpret_cast<const uint4*>(&h1[(size_t)dv2 * 512 + lane * 8]);
        uint4 u3 = *reinterpret_cast<const uint4*>(&h1[(size_t)dv3 * 512 + lane * 8]);
        float w0 = att_w(sn + g0), w1 = att_w(sn + g1), w2 = att_w(sn + g2), w3 = att_w(sn + g3);
        rsum += (w0 + w1) + (w2 + w3);
        float f[8];
        unpack8(u0, f);
#pragma unroll
        for (int q = 0; q < 8; q++) acc[q] += w0 * f[q];
        unpack8(u1, f);
#pragma unroll
        for (int q = 0; q < 8; q++) acc[q] += w1 * f[q];
        unpack8(u2, f);
#pragma unroll
        for (int q = 0; q < 8; q++) acc[q] += w2 * f[q];
        unpack8(u3, f);
#pragma unroll
        for (int q = 0; q < 8; q++) acc[q] += w3 * f[q];
    }
    for (; i < end; i++) {
        int dv = colidx[i];
        float w = att_w(sn + d1[(dv << 3) + h]);
        rsum += w;
        uint4 u = *reinterpret_cast<const uint4*>(&h1[(size_t)dv * 512 + lane * 8]);
        float f[8]; unpack8(u, f);
#pragma unroll
        for (int q = 0; q < 8; q++) acc[q] += w * f[q];
    }
    float inv = 1.f / rsum;
    uint ov[4];
#pragma unroll
    for (int p = 0; p < 4; p++) {
        float v0 = acc[2 * p] * inv;     v0 = v0 > 0.f ? v0 : __expf(v0) - 1.f;
        float v1 = acc[2 * p + 1] * inv; v1 = v1 > 0.f ? v1 : __expf(v1) - 1.f;
        ov[p] = (uint)f32_to_bf16(v0) | ((uint)f32_to_bf16(v1) << 16);
    }
    uint4 o; o.x = ov[0]; o.y = ov[1]; o.z = ov[2]; o.w = ov[3];
    *reinterpret_cast<uint4*>(&x[(size_t)n * 512 + lane * 8]) = o;
}

// layer-2 aggregation + final elu over node range [nb, ne), edge loop unrolled x4.
__global__ __launch_bounds__(256) void agg2_kernel(const ushort* __restrict__ h2,
                                                   const float* __restrict__ s2,
                                                   const float* __restrict__ d2,
                                                   const int* __restrict__ rowptr,
                                                   const int* __restrict__ colidx,
                                                   float* __restrict__ out, int nb, int ne) {
    int lane = threadIdx.x & 63;
    int n = nb + (blockIdx.x << 2) + (threadIdx.x >> 6);
    if (n >= ne) return;
    int c0 = lane * 8;
    float sn = s2[n];
    float acc[8] = {0.f, 0.f, 0.f, 0.f, 0.f, 0.f, 0.f, 0.f};
    float rsum = 0.f;
    int beg = rowptr[n], end = rowptr[n + 1];
    int i = beg;
    for (; i + 4 <= end; i += 4) {
        int dv0 = colidx[i], dv1 = colidx[i + 1], dv2 = colidx[i + 2], dv3 = colidx[i + 3];
        float g0 = d2[dv0], g1 = d2[dv1], g2 = d2[dv2], g3 = d2[dv3];
        uint4 u0 = *reinterpret_cast<const uint4*>(&h2[(size_t)dv0 * 512 + c0]);
        uint4 u1 = *reinterpret_cast<const uint4*>(&h2[(size_t)dv1 * 512 + c0]);
        uint4 u2 = *reinterpret_cast<const uint4*>(&h2[(size_t)dv2 * 512 + c0]);
        uint4 u3 = *reinterpret_cast<const uint4*>(&h2[(size_t)dv3 * 512 + c0]);
        float w0 = att_w(sn + g0), w1 = att_w(sn + g1), w2 = att_w(sn + g2), w3 = att_w(sn + g3);
        rsum += (w0 + w1) + (w2 + w3);
        float f[8];
        unpack8(u0, f);
#pragma unroll
        for (int q = 0; q < 8; q++) acc[q] += w0 * f[q];
        unpack8(u1, f);
#pragma unroll
        for (int q = 0; q < 8; q++) acc[q] += w1 * f[q];
        unpack8(u2, f);
#pragma unroll
        for (int q = 0; q < 8; q++) acc[q] += w2 * f[q];
        unpack8(u3, f);
#pragma unroll
        for (int q = 0; q < 8; q++) acc[q] += w3 * f[q];
    }
    for (; i < end; i++) {
        int dv = colidx[i];
        float w = att_w(sn + d2[dv]);
        rsum += w;
        uint4 u = *reinterpret_cast<const uint4*>(&h2[(size_t)dv * 512 + c0]);
        float f[8]; unpack8(u, f);
#pragma unroll
        for (int q = 0; q < 8; q++) acc[q] += w * f[q];
    }
    float inv = 1.f / rsum;
#pragma unroll
    for (int q = 0; q < 8; q++) {
        int c = c0 + q;
        if (c < NCLASS) {
            float v = acc[q] * inv;
            v = v > 0.f ? v : __expf(v) - 1.f;
            out[(size_t)n * NCLASS + c] = v;
        }
    }
}

extern "C" void kernel_launch(void* const* d_in, const int* in_sizes, int n_in,
                              void* d_out, int out_size, void* d_ws, size_t ws_size,
                              hipStream_t stream) {
    const float* features = (const float*)d_in[0];
    const int* edge_index = (const int*)d_in[1];
    const float* W = (const float*)d_in[2];
    const float* a = (const float*)d_in[3];
    const float* out_W = (const float*)d_in[4];
    const float* out_a = (const float*)d_in[5];
    float* out = (float*)d_out;

    int N = in_sizes[0] / NFEAT;
    int E = in_sizes[1] / 2;
    const int* src = edge_index;
    const int* dst = edge_index + E;

    char* base = (char*)d_ws;
    size_t off = 0;
    auto alloc = [&](size_t bytes) -> char* {
        char* r = base + off;
        off += (bytes + 255) & ~(size_t)255;
        return r;
    };
    ushort* featb = (ushort*)alloc((size_t)N * 512 * 2);
    ushort* h1b   = (ushort*)alloc((size_t)N * 512 * 2);
    ushort* xb    = (ushort*)alloc((size_t)N * 512 * 2);
    ushort* h2b   = featb;  // features-bf16 dead after GEMM-1; alias to cut peak ws
    ushort* w1t   = (ushort*)alloc(512 * 512 * 2);
    ushort* w2t   = (ushort*)alloc(512 * 512 * 2);
    float* s1 = (float*)alloc((size_t)N * 8 * 4);
    float* d1 = (float*)alloc((size_t)N * 8 * 4);
    float* s2 = (float*)alloc((size_t)N * 4);
    float* d2 = (float*)alloc((size_t)N * 4);
    float* oas = (float*)alloc(512 * 4);
    float* oad = (float*)alloc(512 * 4);
    int* rowptr = (int*)alloc((size_t)(N + 1) * 4);
    int* colidx = (int*)alloc((size_t)E * 4);
    int* cnt = (int*)alloc((size_t)N * 4);
    int* cur = (int*)alloc((size_t)N * 4);
    if (off > ws_size) return;

    prep_kernel<<<1024, 256, 0, stream>>>(W, w1t, out_W, w2t, out_a, oas, oad, cnt, cur, N);
    cast_feat_kernel<<<2048, 256, 0, stream>>>(features, featb, N * 512 / 4);
    edge_count_kernel<<<(E + 255) / 256, 256, 0, stream>>>(src, cnt, E);
    scan_kernel<<<1, 1024, 0, stream>>>(cnt, rowptr, N);
    scatter_kernel<<<(E + 255) / 256, 256, 0, stream>>>(src, dst, rowptr, cur, colidx, E);

    int half = (N + 1) / 2;
    int g1 = (half + 3) / 4, g2 = (N - half + 3) / 4;
    dim3 gemm_grid((N + BM - 1) / BM, HID_ALL / BN);
    gemm_bf16_kernel<<<gemm_grid, 256, 0, stream>>>(featb, w1t, h1b, N);
    scores1_kernel<<<(N + 255) / 256, 256, 0, stream>>>(h1b, a, s1, d1, N);
    agg1_kernel<<<g1, 256, 0, stream>>>(h1b, s1, d1, rowptr, colidx, xb, 0, half);
    agg1_kernel<<<g2, 256, 0, stream>>>(h1b, s1, d1, rowptr, colidx, xb, half, N);
    gemm_bf16_kernel<<<gemm_grid, 256, 0, stream>>>(xb, w2t, h2b, N);
    scores2_kernel<<<(N + 255) / 256, 256, 0, stream>>>(h2b, oas, oad, s2, d2, N);
    agg2_kernel<<<g1, 256, 0, stream>>>(h2b, s2, d2, rowptr, colidx, out, 0, half);
    agg2_kernel<<<g2, 256, 0, stream>>>(h2b, s2, d2, rowptr, colidx, out, half, N);
}

// Round 10
// 342.227 us; speedup vs baseline: 1.1962x; 1.1165x over previous
//
#include <hip/hip_runtime.h>
#include <math.h>

typedef __attribute__((ext_vector_type(8))) short short8;
typedef __attribute__((ext_vector_type(4))) float f32x4;

#define NFEAT 512
#define HID_ALL 512
#define NCLASS 500
#define ALPHA 0.2f
#define BM 128
#define BN 128

__device__ __forceinline__ ushort f32_to_bf16(float f) {
    union { float f; unsigned u; } v; v.f = f;
    unsigned u = v.u;
    unsigned r = (u + 0x7FFFu + ((u >> 16) & 1u)) >> 16;
    return (ushort)r;
}
__device__ __forceinline__ void unpack8(uint4 u, float* f) {
    f[0] = __uint_as_float(u.x << 16);
    f[1] = __uint_as_float(u.x & 0xFFFF0000u);
    f[2] = __uint_as_float(u.y << 16);
    f[3] = __uint_as_float(u.y & 0xFFFF0000u);
    f[4] = __uint_as_float(u.z << 16);
    f[5] = __uint_as_float(u.z & 0xFFFF0000u);
    f[6] = __uint_as_float(u.w << 16);
    f[7] = __uint_as_float(u.w & 0xFFFF0000u);
}
__device__ __forceinline__ float att_w(float lg) {
    return __expf(lg > 0.f ? -lg : -ALPHA * lg);
}
__device__ __forceinline__ void gload16(const void* g, void* l) {
    __builtin_amdgcn_global_load_lds(
        (const __attribute__((address_space(1))) unsigned int*)g,
        (__attribute__((address_space(3))) unsigned int*)l,
        16, 0, 0);
}

// fused prep: weight transposes + padded out_a tables + zero CSR counters + zero s2/d2
__global__ void prep_kernel(const float* __restrict__ W, ushort* __restrict__ W1T,
                            const float* __restrict__ oW, ushort* __restrict__ W2T,
                            const float* __restrict__ oa, float* __restrict__ oas,
                            float* __restrict__ oad,
                            int* __restrict__ cnt, int* __restrict__ cur,
                            float* __restrict__ s2, float* __restrict__ d2, int N) {
    int idx = blockIdx.x * blockDim.x + threadIdx.x;
    if (idx < 512 * 512) {
        int c = idx >> 9, f = idx & 511;
        int head = c >> 6, k = c & 63;
        W1T[idx] = f32_to_bf16(W[(head << 15) + (f << 6) + k]);
        float v = (c < NCLASS) ? oW[f * NCLASS + c] : 0.f;
        W2T[idx] = f32_to_bf16(v);
    }
    if (idx < 512) {
        oas[idx] = (idx < NCLASS) ? oa[idx] : 0.f;
        oad[idx] = (idx < NCLASS) ? oa[NCLASS + idx] : 0.f;
    }
    if (idx < N) { cnt[idx] = 0; cur[idx] = 0; s2[idx] = 0.f; d2[idx] = 0.f; }
}

__global__ void cast_feat_kernel(const float* __restrict__ in, ushort* __restrict__ out, int n4) {
    int stride = gridDim.x * blockDim.x;
    for (int i = blockIdx.x * blockDim.x + threadIdx.x; i < n4; i += stride) {
        float4 v = reinterpret_cast<const float4*>(in)[i];
        ushort4 o;
        o.x = f32_to_bf16(v.x); o.y = f32_to_bf16(v.y);
        o.z = f32_to_bf16(v.z); o.w = f32_to_bf16(v.w);
        reinterpret_cast<ushort4*>(out)[i] = o;
    }
}

__global__ void edge_count_kernel(const int* __restrict__ src, int* __restrict__ cnt, int E) {
    int e = blockIdx.x * blockDim.x + threadIdx.x;
    if (e < E) atomicAdd(&cnt[src[e]], 1);
}

__global__ __launch_bounds__(1024) void scan_kernel(const int* __restrict__ cnt,
                                                    int* __restrict__ rowptr, int n) {
    __shared__ int part[1024];
    int t = threadIdx.x;
    int chunk = (n + 1023) >> 10;
    int beg = t * chunk;
    int end = beg + chunk; if (end > n) end = n;
    int s = 0;
    for (int i = beg; i < end; i++) s += cnt[i];
    part[t] = s;
    __syncthreads();
    for (int off = 1; off < 1024; off <<= 1) {
        int v = part[t];
        int add = (t >= off) ? part[t - off] : 0;
        __syncthreads();
        part[t] = v + add;
        __syncthreads();
    }
    int base = (t > 0) ? part[t - 1] : 0;
    for (int i = beg; i < end; i++) { rowptr[i] = base; base += cnt[i]; }
    if (t == 1023) rowptr[n] = part[1023];
}

__global__ void scatter_kernel(const int* __restrict__ src, const int* __restrict__ dst,
                               const int* __restrict__ rowptr, int* __restrict__ cur,
                               int* __restrict__ colidx, int E) {
    int e = blockIdx.x * blockDim.x + threadIdx.x;
    if (e >= E) return;
    int s = src[e];
    int p = rowptr[s] + atomicAdd(&cur[s], 1);
    colidx[p] = dst[e];
}

// GEMM core: BK=64, LDS [128][64] bf16 (128B rows = 32 banks), 16B-chunk XOR swizzle
// (chunk ^ (row&7)) applied on BOTH the per-lane global source of global_load_lds
// (LDS dest stays linear) and the ds_read address -> ~2-way conflicts (free).
// MODE 0: fused scores1 (per-head plain stores). MODE 1: fused scores2 (atomicAdd).
template <int MODE>
__global__ __launch_bounds__(256) void gemm_fused_kernel(const ushort* __restrict__ A,
                                                         const ushort* __restrict__ Bt,
                                                         ushort* __restrict__ C,
                                                         const float* __restrict__ av,
                                                         const float* __restrict__ av2,
                                                         float* __restrict__ sv,
                                                         float* __restrict__ dv,
                                                         int M) {
    __shared__ ushort As[BM * 64];
    __shared__ ushort Bs[BN * 64];
    int m0 = blockIdx.x * BM;
    int n0 = blockIdx.y * BN;
    int t = threadIdx.x;
    int lane = t & 63, wid = t >> 6;
    int wr = wid >> 1, wc = wid & 1;
    int g = lane >> 4, r15 = lane & 15;
    int srow = lane >> 3;        // 0..7 staging row within wave slab
    int schunk = lane & 7;       // 16B chunk 0..7
    f32x4 acc[4][4] = {};
    for (int k0 = 0; k0 < 512; k0 += 64) {
        __syncthreads();
#pragma unroll
        for (int j = 0; j < 4; j++) {
            int rb = j * 32 + wid * 8;              // wave-uniform row base
            int r = rb + srow;
            int ca = (schunk ^ (srow & 7)) << 3;    // pre-swizzled source chunk (elems)
            int rowA = m0 + r; if (rowA >= M) rowA = M - 1;
            gload16(&A[(size_t)rowA * 512 + k0 + ca], &As[rb * 64]);
            int rowB = n0 + r;
            gload16(&Bt[(size_t)rowB * 512 + k0 + ca], &Bs[rb * 64]);
        }
        __syncthreads();
#pragma unroll
        for (int kk = 0; kk < 2; kk++) {
            int coff = ((kk * 4 + g) ^ (r15 & 7)) << 3;  // swizzled read chunk (elems)
            short8 af[4], bfr[4];
#pragma unroll
            for (int mi = 0; mi < 4; mi++)
                af[mi] = *reinterpret_cast<const short8*>(&As[((wr << 6) + mi * 16 + r15) * 64 + coff]);
#pragma unroll
            for (int ni = 0; ni < 4; ni++)
                bfr[ni] = *reinterpret_cast<const short8*>(&Bs[((wc << 6) + ni * 16 + r15) * 64 + coff]);
#pragma unroll
            for (int mi = 0; mi < 4; mi++)
#pragma unroll
                for (int ni = 0; ni < 4; ni++)
                    acc[mi][ni] = __builtin_amdgcn_mfma_f32_16x16x32_bf16(af[mi], bfr[ni], acc[mi][ni], 0, 0, 0);
        }
    }
    int fr = g << 2;
    int col = r15;
    // C store (bf16)
#pragma unroll
    for (int mi = 0; mi < 4; mi++)
#pragma unroll
        for (int ni = 0; ni < 4; ni++)
#pragma unroll
            for (int r = 0; r < 4; r++) {
                int grow = m0 + (wr << 6) + mi * 16 + fr + r;
                if (grow < M) {
                    int gcol = n0 + (wc << 6) + ni * 16 + col;
                    C[(size_t)grow * 512 + gcol] = f32_to_bf16(acc[mi][ni][r]);
                }
            }
    // fused scores from f32 accumulators
    float ws[4], wd[4];
    int h = (n0 >> 6) + wc;  // head for MODE 0
#pragma unroll
    for (int ni = 0; ni < 4; ni++) {
        if (MODE == 0) {
            int k = ni * 16 + col;            // 0..63 within head window
            ws[ni] = av[(h << 7) + k];
            wd[ni] = av[(h << 7) + 64 + k];
        } else {
            int gcol = n0 + (wc << 6) + ni * 16 + col;
            ws[ni] = av[gcol];
            wd[ni] = av2[gcol];
        }
    }
#pragma unroll
    for (int mi = 0; mi < 4; mi++)
#pragma unroll
        for (int r = 0; r < 4; r++) {
            float ps = 0.f, pd = 0.f;
#pragma unroll
            for (int ni = 0; ni < 4; ni++) {
                float v = acc[mi][ni][r];
                ps += v * ws[ni];
                pd += v * wd[ni];
            }
#pragma unroll
            for (int off = 1; off < 16; off <<= 1) {
                ps += __shfl_xor(ps, off);
                pd += __shfl_xor(pd, off);
            }
            int grow = m0 + (wr << 6) + mi * 16 + fr + r;
            if (col == 0 && grow < M) {
                if (MODE == 0) {
                    sv[(grow << 3) + h] = ps;
                    dv[(grow << 3) + h] = pd;
                } else {
                    atomicAdd(&sv[grow], ps);
                    atomicAdd(&dv[grow], pd);
                }
            }
        }
}

// layer-1 aggregation, edge loop unrolled x4.
__global__ __launch_bounds__(256) void agg1_kernel(const ushort* __restrict__ h1,
                                                   const float* __restrict__ s1,
                                                   const float* __restrict__ d1,
                                                   const int* __restrict__ rowptr,
                                                   const int* __restrict__ colidx,
                                                   ushort* __restrict__ x, int N) {
    int lane = threadIdx.x & 63;
    int n = (blockIdx.x << 2) + (threadIdx.x >> 6);
    if (n >= N) return;
    int h = lane >> 3;
    float sn = s1[(n << 3) + h];
    float acc[8] = {0.f, 0.f, 0.f, 0.f, 0.f, 0.f, 0.f, 0.f};
    float rsum = 0.f;
    int beg = rowptr[n], end = rowptr[n + 1];
    int i = beg;
    for (; i + 4 <= end; i += 4) {
        int dv0 = colidx[i], dv1 = colidx[i + 1], dv2 = colidx[i + 2], dv3 = colidx[i + 3];
        float g0 = d1[(dv0 << 3) + h];
        float g1 = d1[(dv1 << 3) + h];
        float g2 = d1[(dv2 << 3) + h];
        float g3 = d1[(dv3 << 3) + h];
        uint4 u0 = *reinterpret_cast<const uint4*>(&h1[(size_t)dv0 * 512 + lane * 8]);
        uint4 u1 = *reinterpret_cast<const uint4*>(&h1[(size_t)dv1 * 512 + lane * 8]);
        uint4 u2 = *reinterpret_cast<const uint4*>(&h1[(size_t)dv2 * 512 + lane * 8]);
        uint4 u3 = *reinterpret_cast<const uint4*>(&h1[(size_t)dv3 * 512 + lane * 8]);
        float w0 = att_w(sn + g0), w1 = att_w(sn + g1), w2 = att_w(sn + g2), w3 = att_w(sn + g3);
        rsum += (w0 + w1) + (w2 + w3);
        float f[8];
        unpack8(u0, f);
#pragma unroll
        for (int q = 0; q < 8; q++) acc[q] += w0 * f[q];
        unpack8(u1, f);
#pragma unroll
        for (int q = 0; q < 8; q++) acc[q] += w1 * f[q];
        unpack8(u2, f);
#pragma unroll
        for (int q = 0; q < 8; q++) acc[q] += w2 * f[q];
        unpack8(u3, f);
#pragma unroll
        for (int q = 0; q < 8; q++) acc[q] += w3 * f[q];
    }
    for (; i < end; i++) {
        int dv = colidx[i];
        float w = att_w(sn + d1[(dv << 3) + h]);
        rsum += w;
        uint4 u = *reinterpret_cast<const uint4*>(&h1[(size_t)dv * 512 + lane * 8]);
        float f[8]; unpack8(u, f);
#pragma unroll
        for (int q = 0; q < 8; q++) acc[q] += w * f[q];
    }
    float inv = 1.f / rsum;
    uint ov[4];
#pragma unroll
    for (int p = 0; p < 4; p++) {
        float v0 = acc[2 * p] * inv;     v0 = v0 > 0.f ? v0 : __expf(v0) - 1.f;
        float v1 = acc[2 * p + 1] * inv; v1 = v1 > 0.f ? v1 : __expf(v1) - 1.f;
        ov[p] = (uint)f32_to_bf16(v0) | ((uint)f32_to_bf16(v1) << 16);
    }
    uint4 o; o.x = ov[0]; o.y = ov[1]; o.z = ov[2]; o.w = ov[3];
    *reinterpret_cast<uint4*>(&x[(size_t)n * 512 + lane * 8]) = o;
}

// layer-2 aggregation + final elu, edge loop unrolled x4.
__global__ __launch_bounds__(256) void agg2_kernel(const ushort* __restrict__ h2,
                                                   const float* __restrict__ s2,
                                                   const float* __restrict__ d2,
                                                   const int* __restrict__ rowptr,
                                                   const int* __restrict__ colidx,
                                                   float* __restrict__ out, int N) {
    int lane = threadIdx.x & 63;
    int n = (blockIdx.x << 2) + (threadIdx.x >> 6);
    if (n >= N) return;
    int c0 = lane * 8;
    float sn = s2[n];
    float acc[8] = {0.f, 0.f, 0.f, 0.f, 0.f, 0.f, 0.f, 0.f};
    float rsum = 0.f;
    int beg = rowptr[n], end = rowptr[n + 1];
    int i = beg;
    for (; i + 4 <= end; i += 4) {
        int dv0 = colidx[i], dv1 = colidx[i + 1], dv2 = colidx[i + 2], dv3 = colidx[i + 3];
        float g0 = d2[dv0], g1 = d2[dv1], g2 = d2[dv2], g3 = d2[dv3];
        uint4 u0 = *reinterpret_cast<const uint4*>(&h2[(size_t)dv0 * 512 + c0]);
        uint4 u1 = *reinterpret_cast<const uint4*>(&h2[(size_t)dv1 * 512 + c0]);
        uint4 u2 = *reinterpret_cast<const uint4*>(&h2[(size_t)dv2 * 512 + c0]);
        uint4 u3 = *reinterpret_cast<const uint4*>(&h2[(size_t)dv3 * 512 + c0]);
        float w0 = att_w(sn + g0), w1 = att_w(sn + g1), w2 = att_w(sn + g2), w3 = att_w(sn + g3);
        rsum += (w0 + w1) + (w2 + w3);
        float f[8];
        unpack8(u0, f);
#pragma unroll
        for (int q = 0; q < 8; q++) acc[q] += w0 * f[q];
        unpack8(u1, f);
#pragma unroll
        for (int q = 0; q < 8; q++) acc[q] += w1 * f[q];
        unpack8(u2, f);
#pragma unroll
        for (int q = 0; q < 8; q++) acc[q] += w2 * f[q];
        unpack8(u3, f);
#pragma unroll
        for (int q = 0; q < 8; q++) acc[q] += w3 * f[q];
    }
    for (; i < end; i++) {
        int dv = colidx[i];
        float w = att_w(sn + d2[dv]);
        rsum += w;
        uint4 u = *reinterpret_cast<const uint4*>(&h2[(size_t)dv * 512 + c0]);
        float f[8]; unpack8(u, f);
#pragma unroll
        for (int q = 0; q < 8; q++) acc[q] += w * f[q];
    }
    float inv = 1.f / rsum;
#pragma unroll
    for (int q = 0; q < 8; q++) {
        int c = c0 + q;
        if (c < NCLASS) {
            float v = acc[q] * inv;
            v = v > 0.f ? v : __expf(v) - 1.f;
            out[(size_t)n * NCLASS + c] = v;
        }
    }
}

extern "C" void kernel_launch(void* const* d_in, const int* in_sizes, int n_in,
                              void* d_out, int out_size, void* d_ws, size_t ws_size,
                              hipStream_t stream) {
    const float* features = (const float*)d_in[0];
    const int* edge_index = (const int*)d_in[1];
    const float* W = (const float*)d_in[2];
    const float* a = (const float*)d_in[3];
    const float* out_W = (const float*)d_in[4];
    const float* out_a = (const float*)d_in[5];
    float* out = (float*)d_out;

    int N = in_sizes[0] / NFEAT;
    int E = in_sizes[1] / 2;
    const int* src = edge_index;
    const int* dst = edge_index + E;

    char* base = (char*)d_ws;
    size_t off = 0;
    auto alloc = [&](size_t bytes) -> char* {
        char* r = base + off;
        off += (bytes + 255) & ~(size_t)255;
        return r;
    };
    ushort* featb = (ushort*)alloc((size_t)N * 512 * 2);
    ushort* h1b   = (ushort*)alloc((size_t)N * 512 * 2);
    ushort* xb    = (ushort*)alloc((size_t)N * 512 * 2);
    ushort* h2b   = featb;  // features-bf16 dead after GEMM-1; alias to cut peak ws
    ushort* w1t   = (ushort*)alloc(512 * 512 * 2);
    ushort* w2t   = (ushort*)alloc(512 * 512 * 2);
    float* s1 = (float*)alloc((size_t)N * 8 * 4);
    float* d1 = (float*)alloc((size_t)N * 8 * 4);
    float* s2 = (float*)alloc((size_t)N * 4);
    float* d2 = (float*)alloc((size_t)N * 4);
    float* oas = (float*)alloc(512 * 4);
    float* oad = (float*)alloc(512 * 4);
    int* rowptr = (int*)alloc((size_t)(N + 1) * 4);
    int* colidx = (int*)alloc((size_t)E * 4);
    int* cnt = (int*)alloc((size_t)N * 4);
    int* cur = (int*)alloc((size_t)N * 4);
    if (off > ws_size) return;

    prep_kernel<<<1024, 256, 0, stream>>>(W, w1t, out_W, w2t, out_a, oas, oad, cnt, cur, s2, d2, N);
    cast_feat_kernel<<<2048, 256, 0, stream>>>(features, featb, N * 512 / 4);
    edge_count_kernel<<<(E + 255) / 256, 256, 0, stream>>>(src, cnt, E);
    scan_kernel<<<1, 1024, 0, stream>>>(cnt, rowptr, N);
    scatter_kernel<<<(E + 255) / 256, 256, 0, stream>>>(src, dst, rowptr, cur, colidx, E);

    dim3 gemm_grid((N + BM - 1) / BM, HID_ALL / BN);
    gemm_fused_kernel<0><<<gemm_grid, 256, 0, stream>>>(featb, w1t, h1b, a, nullptr, s1, d1, N);
    agg1_kernel<<<(N + 3) / 4, 256, 0, stream>>>(h1b, s1, d1, rowptr, colidx, xb, N);
    gemm_fused_kernel<1><<<gemm_grid, 256, 0, stream>>>(xb, w2t, h2b, oas, oad, s2, d2, N);
    agg2_kernel<<<(N + 3) / 4, 256, 0, stream>>>(h2b, s2, d2, rowptr, colidx, out, N);
}